// Round 1
// 288.439 us; speedup vs baseline: 1.1212x; 1.1212x over previous
//
#include <hip/hip_runtime.h>

// Conv_Attention: q,k,v = causal_conv1d(x, W*) ; S = qk^T/sqrt(U);
// softmax over QUERY axis (per-column of S); out = P @ v.
// B=8, T=2048, Cin=U=512, K=3.
//
// Round 8: replace the m97-class 2-barrier GEMM (MfmaUtil 29%, ~700 TF) with
// the 256^2 8-phase counted-vmcnt schedule (T2 swizzle + T3/T4 + T5 setprio):
//  - BM=256, BK=64, 8 waves (512 thr), 16x16x32 bf16 MFMA, dbuf 128 KiB LDS
//  - chunk-XOR swizzle (chunk ^= row&7) pre-applied on the GLOBAL source
//    (global_load_lds dest must be linear), inverted on ds_read_b128
//  - 8 barriered phases / 2 K-tiles; 1 half-tile staged per phase;
//    s_waitcnt vmcnt(4) only at phases 3/7 (never 0 in the loop)
//  - MODE 0: QKV conv GEMM (BN=256, grid 8x6x8)
//    MODE 1: scores, exp(S-16) + 8 column-sum partials (BN=256, grid 8x8x8)
//    MODE 2: ctx P@Vt^T fp32 out (BN=128 so grid = 256 blocks = 1/CU)

#define B_   8
#define T_   2048
#define D_   512
#define KC_  1536
#define TPAD_ 2050

using short8   = __attribute__((ext_vector_type(8))) short;
using float4v  = __attribute__((ext_vector_type(4))) float;

__device__ __forceinline__ float bf2f(unsigned short b) {
  unsigned u = ((unsigned)b) << 16;
  float f; __builtin_memcpy(&f, &u, 4); return f;
}
__device__ __forceinline__ unsigned short f2bf(float f) {
  unsigned u; __builtin_memcpy(&u, &f, 4);
  u += 0x7fffu + ((u >> 16) & 1u);          // RNE (finite inputs only)
  return (unsigned short)(u >> 16);
}

__device__ __forceinline__ void gld16(const void* g, void* l) {
  __builtin_amdgcn_global_load_lds((__attribute__((address_space(1))) void*)g,
                                   (__attribute__((address_space(3))) void*)l,
                                   16, 0, 0);
}

__device__ __forceinline__ float4v mfma16(short8 a, short8 b, float4v c) {
  return __builtin_amdgcn_mfma_f32_16x16x32_bf16(a, b, c, 0, 0, 0);
}

// ---------------- prep: pad + cast x ----------------
__global__ __launch_bounds__(256) void prep_x(const float* __restrict__ x,
                                              unsigned short* __restrict__ xpad) {
  const int b = blockIdx.y;
  const int i = (blockIdx.x * 256 + threadIdx.x) * 4;   // grid.x=1025 -> exactly 2050*512
  const int t = i >> 9;
  unsigned short* dst = xpad + (size_t)b * (TPAD_ * D_) + i;
  if (t < 2) {
    dst[0] = 0; dst[1] = 0; dst[2] = 0; dst[3] = 0;
  } else {
    const float* sp = x + ((size_t)b * T_ + (t - 2)) * D_ + (i & 511);
    float4v v = *(const float4v*)sp;
    dst[0] = f2bf(v[0]); dst[1] = f2bf(v[1]); dst[2] = f2bf(v[2]); dst[3] = f2bf(v[3]);
  }
}

// ---------------- bias concat ----------------
__global__ __launch_bounds__(256) void concat_bias(const float* __restrict__ bq,
                                                   const float* __restrict__ bk,
                                                   const float* __restrict__ bv,
                                                   float* __restrict__ out) {
  const int i = blockIdx.x * 256 + threadIdx.x;   // grid 6 -> 1536
  float v = (i < 512) ? bq[i] : ((i < 1024) ? bk[i - 512] : bv[i - 1024]);
  out[i] = v;
}

// ---------------- W transpose, all three in one launch ----------------
__global__ __launch_bounds__(256) void transpose_w3(const float* __restrict__ Wq,
                                                    const float* __restrict__ Wk,
                                                    const float* __restrict__ Wv,
                                                    unsigned short* __restrict__ Wt) {
  __shared__ unsigned short tile[64][65];
  const float* s = (blockIdx.z == 0) ? Wq : (blockIdx.z == 1) ? Wk : Wv;
  unsigned short* d = Wt + (size_t)blockIdx.z * D_ * KC_;
  const int r0 = blockIdx.x * 64, c0 = blockIdx.y * 64;
  const int tc = threadIdx.x & 63, tg = threadIdx.x >> 6;
#pragma unroll
  for (int i = 0; i < 16; i++) {
    const int r = i * 4 + tg;
    tile[r][tc] = f2bf(s[(size_t)(r0 + r) * D_ + (c0 + tc)]);
  }
  __syncthreads();
#pragma unroll
  for (int i = 0; i < 16; i++) {
    const int rr = i * 4 + tg;
    d[(size_t)(c0 + rr) * KC_ + (r0 + tc)] = tile[tc][rr];
  }
}

// ---------------- V transpose ----------------
__global__ __launch_bounds__(256) void transpose_v(const unsigned short* __restrict__ src,
                                                   unsigned short* __restrict__ dst) {
  __shared__ unsigned short tile[64][65];
  const unsigned short* s = src + (size_t)blockIdx.z * T_ * KC_;
  unsigned short* d = dst + (size_t)blockIdx.z * D_ * T_;
  const int r0 = blockIdx.x * 64, c0 = blockIdx.y * 64;
  const int tc = threadIdx.x & 63, tg = threadIdx.x >> 6;
#pragma unroll
  for (int i = 0; i < 16; i++) {
    const int r = i * 4 + tg;
    tile[r][tc] = s[(size_t)(r0 + r) * KC_ + (c0 + tc)];
  }
  __syncthreads();
#pragma unroll
  for (int i = 0; i < 16; i++) {
    const int rr = i * 4 + tg;
    d[(size_t)(c0 + rr) * T_ + (r0 + tc)] = tile[tc][rr];
  }
}

// ---------------- combine: inv[k] = 1 / sum of 8 partial colsums ----------------
__global__ __launch_bounds__(256) void stats_combine(const float* __restrict__ pl,
                                                     long long sPz,
                                                     float* __restrict__ inv,
                                                     long long sIz) {
  const size_t z = blockIdx.z;
  const int col = blockIdx.x * 256 + threadIdx.x;
  float L = 0.f;
#pragma unroll
  for (int mb = 0; mb < 8; mb++)
    L += pl[z * (size_t)sPz + (size_t)mb * T_ + col];
  inv[z * (size_t)sIz + col] = 1.0f / L;
}

// ---------------- scale Vt rows: Vt[d][k] *= inv[k] ----------------
__global__ __launch_bounds__(256) void scale_vt(unsigned short* __restrict__ Vt,
                                                long long sVz,
                                                const float* __restrict__ inv,
                                                long long sIz) {
  const size_t z = blockIdx.z;
  unsigned short* Vb = Vt + z * (size_t)sVz;
  const float* iv = inv + z * (size_t)sIz;
  const int idx = (blockIdx.x * 256 + threadIdx.x) * 8;  // grid.x=512 -> 512*2048
  const int k = idx & (T_ - 1);
  short8 v = *(const short8*)(Vb + idx);
  float4v i0 = *(const float4v*)(iv + k);
  float4v i1 = *(const float4v*)(iv + k + 4);
  short8 o;
#pragma unroll
  for (int j = 0; j < 8; j++) {
    float s = (j < 4) ? i0[j & 3] : i1[j & 3];
    o[j] = (short)f2bf(bf2f((unsigned short)v[j]) * s);
  }
  *(short8*)(Vb + idx) = o;
}

// ================= 8-phase 256-row GEMM: C = A * B'^T =================
// A [M][K] bf16 row-major (lda), B' [N][K] bf16 row-major (ldb), BK=64.
// Phase template per K-tile (4 phases): reads q(0,0)+, q(0,1), q(1,1), q(1,0);
// all-A read done by ph2, all-B by ph1 -> stage slots derived below.

#define RD_A(MH, BUF)                                                        \
  {                                                                          \
    const unsigned short* p_ = lds + (BUF) * 16384 + aoff + (MH) * 4096;     \
    _Pragma("unroll") for (int f_ = 0; f_ < 4; ++f_) {                       \
      afr[MH][f_][0] = *(const short8*)(p_ + f_ * 1024 + q0);                \
      afr[MH][f_][1] = *(const short8*)(p_ + f_ * 1024 + q1);                \
    }                                                                        \
  }

#define RD_B(NH, BUF)                                                        \
  {                                                                          \
    const unsigned short* p_ =                                               \
        lds + 32768 + (BUF) * BLD + boff + (NH) * NFQ * 1024;                \
    _Pragma("unroll") for (int f_ = 0; f_ < NFQ; ++f_) {                     \
      bfr[NH][f_][0] = *(const short8*)(p_ + f_ * 1024 + q0);                \
      bfr[NH][f_][1] = *(const short8*)(p_ + f_ * 1024 + q1);                \
    }                                                                        \
  }

#define MMA(MH, NH)                                                          \
  __builtin_amdgcn_s_setprio(1);                                             \
  _Pragma("unroll") for (int s_ = 0; s_ < 2; ++s_)                           \
  _Pragma("unroll") for (int f_ = 0; f_ < 4; ++f_)                           \
  _Pragma("unroll") for (int g_ = 0; g_ < NFQ; ++g_)                         \
      acc[(MH) * 4 + f_][(NH) * NFQ + g_] =                                  \
          mfma16(afr[MH][f_][s_], bfr[NH][g_][s_],                           \
                 acc[(MH) * 4 + f_][(NH) * NFQ + g_]);                       \
  __builtin_amdgcn_s_setprio(0);

#define PH_MID                                                               \
  __builtin_amdgcn_s_barrier();                                              \
  asm volatile("s_waitcnt lgkmcnt(0)" ::: "memory");                         \
  __builtin_amdgcn_sched_barrier(0);

#define PH_END __builtin_amdgcn_s_barrier();

#define VMW                                                                  \
  do {                                                                       \
    if constexpr (BN == 256)                                                 \
      asm volatile("s_waitcnt vmcnt(4)" ::: "memory");                       \
    else                                                                     \
      asm volatile("s_waitcnt vmcnt(2)" ::: "memory");                       \
  } while (0)

template <int MODE, int BN>
__global__ __launch_bounds__(512, 2)
void gemm8(const unsigned short* __restrict__ A, long long sAz, int lda,
           const unsigned short* __restrict__ Bm, long long sBz, int ldb,
           void* __restrict__ Out, long long sOz, int ldo,
           const float* __restrict__ bias,
           float* __restrict__ pl, long long sPz,
           int Kdim, float scale) {
  constexpr int NFN = BN / 64;      // n-fragments per wave (4 or 2)
  constexpr int NFQ = NFN / 2;      // n-fragments per quadrant (2 or 1)
  constexpr int BLD = BN * 64;      // elems per B buffer
  __shared__ unsigned short lds[32768 + 2 * BLD];   // A dbuf 64K + B dbuf

  const int tid = threadIdx.x;
  const int l = tid & 63;
  const int wv = tid >> 6;
  const int wm = wv >> 2, wn = wv & 3;              // 2 x 4 wave grid
  const int l15 = l & 15, hi = l >> 4, l7 = l & 7;
  const size_t z = blockIdx.z;
  const unsigned short* Ab = A + z * (size_t)sAz;
  const unsigned short* Bb = Bm + z * (size_t)sBz;
  const int m0 = blockIdx.x * 256, n0 = blockIdx.y * BN;
  const int NT = Kdim >> 6;
  const int NIT = NT >> 1;

  // ---- staging: LDS linear [row][8 chunks of 16B]; global pre-swizzled
  //      so LDS[row][p] holds global chunk p ^ (row&7).
  const int srow = tid >> 3;                                  // 0..63
  const int cswz = ((tid & 7) ^ ((tid >> 3) & 7)) << 3;       // elem offset
  const unsigned short* gA = Ab + (size_t)(m0 + srow) * lda + cswz;
  const unsigned short* gB = Bb + (size_t)(n0 + srow) * ldb + cswz;

  auto stgA = [&](int buf, int h, int kt) {
    if (kt >= NT) kt = NT - 1;                      // tail: harmless reload
    unsigned short* d = lds + buf * 16384 + h * 8192 + tid * 8;
    const unsigned short* g = gA + (size_t)(h * 128) * lda + kt * 64;
    gld16(g, d);
    gld16(g + (size_t)64 * lda, d + 4096);
  };
  auto stgB = [&](int buf, int h, int kt) {
    if (kt >= NT) kt = NT - 1;
    unsigned short* d = lds + 32768 + buf * BLD + h * (BLD / 2) + tid * 8;
    const unsigned short* g = gB + (size_t)(h * (BN / 2)) * ldb + kt * 64;
    gld16(g, d);
    if constexpr (BN == 256) gld16(g + (size_t)64 * ldb, d + 4096);
  };

  // ---- fragment read addressing (inverse swizzle on ds_read_b128)
  const int aoff = (wm * 128 + l15) * 64;
  const int boff = (wn * (BN / 4) + l15) * 64;
  const int q0 = ((0 + hi) ^ l7) << 3;              // k-slice 0 chunk
  const int q1 = ((4 + hi) ^ l7) << 3;              // k-slice 1 chunk

  short8 afr[2][4][2];
  short8 bfr[2][NFQ][2];
  float4v acc[8][NFN];
#pragma unroll
  for (int i = 0; i < 8; ++i)
#pragma unroll
    for (int j = 0; j < NFN; ++j)
#pragma unroll
      for (int r = 0; r < 4; ++r) acc[i][j][r] = 0.f;

  // ---- prologue: tile0 fully + tile1 B-halves; leave tile1.B in flight
  stgB(0, 0, 0); stgB(0, 1, 0);
  stgA(0, 0, 0); stgA(0, 1, 0);
  stgB(1, 0, 1); stgB(1, 1, 1);
  VMW;
  __builtin_amdgcn_s_barrier();
  __builtin_amdgcn_sched_barrier(0);

  // ---- main loop: 8 phases = 2 K-tiles. vmcnt(4|2) at p3/p7 only.
  for (int it = 0; it < NIT; ++it) {
    const int kt = 2 * it;
    // p0: q(0,0) buf0      | stage A0(t+1)->buf1
    RD_A(0, 0); RD_B(0, 0);
    stgA(1, 0, kt + 1);
    PH_MID; MMA(0, 0); PH_END;
    // p1: q(0,1) buf0      | stage A1(t+1)->buf1
    RD_B(1, 0);
    stgA(1, 1, kt + 1);
    PH_MID; MMA(0, 1); PH_END;
    // p2: q(1,1) buf0      | stage B0(t+2)->buf0   (buf0-B reads done @p1)
    RD_A(1, 0);
    stgB(0, 0, kt + 2);
    PH_MID; MMA(1, 1); PH_END;
    // p3: q(1,0) buf0      | stage B1(t+2)->buf0 ; vmcnt -> tile t+1 landed
    stgB(0, 1, kt + 2);
    PH_MID; MMA(1, 0); VMW; PH_END;
    // p4: q(0,0) buf1      | stage A0(t+2)->buf0   (buf0-A reads done @p2)
    RD_A(0, 1); RD_B(0, 1);
    stgA(0, 0, kt + 2);
    PH_MID; MMA(0, 0); PH_END;
    // p5: q(0,1) buf1      | stage A1(t+2)->buf0
    RD_B(1, 1);
    stgA(0, 1, kt + 2);
    PH_MID; MMA(0, 1); PH_END;
    // p6: q(1,1) buf1      | stage B0(t+3)->buf1   (buf1-B reads done @p5)
    RD_A(1, 1);
    stgB(1, 0, kt + 3);
    PH_MID; MMA(1, 1); PH_END;
    // p7: q(1,0) buf1      | stage B1(t+3)->buf1 ; vmcnt -> tile t+2 landed
    stgB(1, 1, kt + 3);
    PH_MID; MMA(1, 0); VMW; PH_END;
  }

  // ---- epilogue: C/D col = lane&15, row = (lane>>4)*4 + reg
  const int r0 = m0 + wm * 128 + hi * 4;
  const int c0 = n0 + wn * (BN / 4) + l15;

  if constexpr (MODE == 2) {
    float* O = (float*)Out + z * (size_t)sOz;
#pragma unroll
    for (int fm = 0; fm < 8; ++fm)
#pragma unroll
      for (int fn = 0; fn < NFN; ++fn)
#pragma unroll
        for (int r = 0; r < 4; ++r)
          O[(size_t)(r0 + fm * 16 + r) * ldo + (c0 + fn * 16)] =
              acc[fm][fn][r] * scale;
  } else if constexpr (MODE == 0) {
    unsigned short* O = (unsigned short*)Out + z * (size_t)sOz;
#pragma unroll
    for (int fn = 0; fn < NFN; ++fn) {
      const float badd = bias[c0 + fn * 16];
#pragma unroll
      for (int fm = 0; fm < 8; ++fm)
#pragma unroll
        for (int r = 0; r < 4; ++r)
          O[(size_t)(r0 + fm * 16 + r) * ldo + (c0 + fn * 16)] =
              f2bf(acc[fm][fn][r] * scale + badd);
    }
  } else {  // MODE 1: P_raw = exp(S*scale - 16) + per-block column sums
    unsigned short* O = (unsigned short*)Out + z * (size_t)sOz;
    float cs[NFN];
#pragma unroll
    for (int fn = 0; fn < NFN; ++fn) cs[fn] = 0.f;
#pragma unroll
    for (int fm = 0; fm < 8; ++fm)
#pragma unroll
      for (int fn = 0; fn < NFN; ++fn)
#pragma unroll
        for (int r = 0; r < 4; ++r) {
          float e = __expf(acc[fm][fn][r] * scale - 16.f);   // |S*scale| <~ 25
          cs[fn] += e;
          O[(size_t)(r0 + fm * 16 + r) * ldo + (c0 + fn * 16)] = f2bf(e);
        }
    // reduce over the 4 row-groups (lane>>4) inside the wave
#pragma unroll
    for (int fn = 0; fn < NFN; ++fn) {
      cs[fn] += __shfl_xor(cs[fn], 16, 64);
      cs[fn] += __shfl_xor(cs[fn], 32, 64);
    }
    __syncthreads();
    float* red = (float*)(lds + 32768);     // scratch in B region (A region
    if (hi == 0) {                          // may still receive tail stages)
#pragma unroll
      for (int fn = 0; fn < NFN; ++fn)
        red[wm * 256 + wn * 64 + fn * 16 + l15] = cs[fn];
    }
    __syncthreads();
    if (tid < 256)
      pl[z * (size_t)sPz + (size_t)blockIdx.x * T_ + (n0 + tid)] =
          red[tid] + red[256 + tid];
  }
}

// ---------------- host ----------------
extern "C" void kernel_launch(void* const* d_in, const int* in_sizes, int n_in,
                              void* d_out, int out_size, void* d_ws, size_t ws_size,
                              hipStream_t stream) {
  const float* x  = (const float*)d_in[0];
  const float* Wq = (const float*)d_in[1];
  const float* bq = (const float*)d_in[2];
  const float* Wk = (const float*)d_in[3];
  const float* bk = (const float*)d_in[4];
  const float* Wv = (const float*)d_in[5];
  const float* bv = (const float*)d_in[6];

  char* ws = (char*)d_ws;
  auto alloc = [&](size_t bytes) {
    char* p = ws; ws += (bytes + 255) & ~(size_t)255; return p;
  };
  unsigned short* xpad = (unsigned short*)alloc((size_t)B_ * TPAD_ * D_ * 2);
  unsigned short* Wt   = (unsigned short*)alloc((size_t)KC_ * KC_ * 2);     // [1536 u][1536 k]
  float*          bcat = (float*)alloc((size_t)KC_ * 4);
  unsigned short* QKV  = (unsigned short*)alloc((size_t)B_ * T_ * KC_ * 2); // [B][T][1536]
  unsigned short* Vt   = (unsigned short*)alloc((size_t)B_ * D_ * T_ * 2);
  float* invb = (float*)alloc((size_t)B_ * T_ * 4);
  float* pl   = (float*)alloc((size_t)B_ * 8 * T_ * 4);
  size_t used = (size_t)(ws - (char*)d_ws);
  const size_t sAll = (size_t)B_ * T_ * T_ * 2;   // bf16 P, all batches
  const size_t sOne = (size_t)T_ * T_ * 2;
  const int NB = (used + sAll <= ws_size) ? B_ : 1;  // ws-adaptive batching
  unsigned short* Sb = (unsigned short*)alloc(NB == B_ ? sAll : sOne);

  prep_x<<<dim3(1025, B_), 256, 0, stream>>>(x, xpad);
  concat_bias<<<dim3(6), 256, 0, stream>>>(bq, bk, bv, bcat);
  transpose_w3<<<dim3(24, 8, 3), 256, 0, stream>>>(Wq, Wk, Wv, Wt);

  // one QKV GEMM: M=2048/batch, N=1536, K=1536
  gemm8<0, 256><<<dim3(8, 6, B_), 512, 0, stream>>>(
      xpad, (long long)TPAD_ * D_, D_,
      Wt, 0, KC_,
      QKV, (long long)T_ * KC_, KC_,
      bcat, nullptr, 0, KC_, 1.0f);

  // V slice [T][512] (row stride 1536) -> Vt [512][2048]
  transpose_v<<<dim3(32, 8, B_), 256, 0, stream>>>(QKV + 2 * D_, Vt);

  const float scale = 0.044194173824159216f;  // 1/sqrt(512)
  for (int b0 = 0; b0 < B_; b0 += NB) {
    const unsigned short* Qp = QKV + (size_t)b0 * T_ * KC_;          // +0
    const unsigned short* Kp = QKV + (size_t)b0 * T_ * KC_ + D_;     // +512
    // P_raw = exp(S-16) + partial column sums (8 m-blocks)
    gemm8<1, 256><<<dim3(8, 8, NB), 512, 0, stream>>>(
        Qp, (long long)T_ * KC_, KC_,
        Kp, (long long)T_ * KC_, KC_,
        Sb, (long long)T_ * T_, T_,
        nullptr, pl + (size_t)b0 * 8 * T_, (long long)8 * T_,
        D_, scale);
    stats_combine<<<dim3(8, 1, NB), 256, 0, stream>>>(
        pl + (size_t)b0 * 8 * T_, (long long)8 * T_,
        invb + (size_t)b0 * T_, T_);
    scale_vt<<<dim3(512, 1, NB), 256, 0, stream>>>(
        Vt + (size_t)b0 * D_ * T_, (long long)D_ * T_,
        invb + (size_t)b0 * T_, T_);
    // ctx: out = P_raw @ Vt'^T, 256x128 tiles -> 256 blocks (1/CU)
    gemm8<2, 128><<<dim3(8, 4, NB), 512, 0, stream>>>(
        Sb, (long long)T_ * T_, T_,
        Vt + (size_t)b0 * D_ * T_, (long long)D_ * T_, T_,
        (float*)d_out + (size_t)b0 * T_ * D_, (long long)T_ * D_, D_,
        nullptr, nullptr, 0, T_, 1.0f);
  }
}

// Round 2
// 282.491 us; speedup vs baseline: 1.1448x; 1.0211x over previous
//
#include <hip/hip_runtime.h>

// Conv_Attention: q,k,v = causal_conv1d(x, W*) ; S = qk^T/sqrt(U);
// softmax over QUERY axis (per-column of S); out = P @ v.
// B=8, T=2048, Cin=U=512, K=3.
//
// Round 9: round-8's 8-phase port reached steady-state ~51% MfmaUtil but the
// QKV grid (8x6x8 = 384 blocks) is 1.5 dispatch rounds on 256 CUs -> 25% tail
// loss (97 us where steady is ~73). Fix: generalize gemm8 over (BN, WM, WN)
// and run QKV as BN=192 with a 4x2 wave grid -> grid 8x8x8 = 512 = exactly
// 2.0 rounds. Scores <1,256,2,4> and ctx <2,128,2,4> instantiations are
// unchanged from the passing round-8 kernel.
//
// vmcnt ledger (GB = BN/64 = B-tile staging loads; A-tile = 4):
//   prologue issues B(t0)[GB] A(t0)[4] B(t1)[GB]; vmcnt(GB) retires t0.
//   loop: p0,p1 +A(t+1)[4]; p2,p3 +B(t+2)[GB]; vmcnt(GB) at p3 retires
//   B(t+1)+A(t+1) (the GB+4 oldest) -> buf of tile t+1 fully landed before
//   p4 reads it; symmetric at p7. Never vmcnt(0) in the loop.

#define B_   8
#define T_   2048
#define D_   512
#define KC_  1536
#define TPAD_ 2050

using short8   = __attribute__((ext_vector_type(8))) short;
using float4v  = __attribute__((ext_vector_type(4))) float;

__device__ __forceinline__ float bf2f(unsigned short b) {
  unsigned u = ((unsigned)b) << 16;
  float f; __builtin_memcpy(&f, &u, 4); return f;
}
__device__ __forceinline__ unsigned short f2bf(float f) {
  unsigned u; __builtin_memcpy(&u, &f, 4);
  u += 0x7fffu + ((u >> 16) & 1u);          // RNE (finite inputs only)
  return (unsigned short)(u >> 16);
}

__device__ __forceinline__ void gld16(const void* g, void* l) {
  __builtin_amdgcn_global_load_lds((__attribute__((address_space(1))) void*)g,
                                   (__attribute__((address_space(3))) void*)l,
                                   16, 0, 0);
}

__device__ __forceinline__ float4v mfma16(short8 a, short8 b, float4v c) {
  return __builtin_amdgcn_mfma_f32_16x16x32_bf16(a, b, c, 0, 0, 0);
}

// ---------------- prep: pad + cast x ----------------
__global__ __launch_bounds__(256) void prep_x(const float* __restrict__ x,
                                              unsigned short* __restrict__ xpad) {
  const int b = blockIdx.y;
  const int i = (blockIdx.x * 256 + threadIdx.x) * 4;   // grid.x=1025 -> exactly 2050*512
  const int t = i >> 9;
  unsigned short* dst = xpad + (size_t)b * (TPAD_ * D_) + i;
  if (t < 2) {
    dst[0] = 0; dst[1] = 0; dst[2] = 0; dst[3] = 0;
  } else {
    const float* sp = x + ((size_t)b * T_ + (t - 2)) * D_ + (i & 511);
    float4v v = *(const float4v*)sp;
    dst[0] = f2bf(v[0]); dst[1] = f2bf(v[1]); dst[2] = f2bf(v[2]); dst[3] = f2bf(v[3]);
  }
}

// ---------------- bias concat ----------------
__global__ __launch_bounds__(256) void concat_bias(const float* __restrict__ bq,
                                                   const float* __restrict__ bk,
                                                   const float* __restrict__ bv,
                                                   float* __restrict__ out) {
  const int i = blockIdx.x * 256 + threadIdx.x;   // grid 6 -> 1536
  float v = (i < 512) ? bq[i] : ((i < 1024) ? bk[i - 512] : bv[i - 1024]);
  out[i] = v;
}

// ---------------- W transpose, all three in one launch ----------------
__global__ __launch_bounds__(256) void transpose_w3(const float* __restrict__ Wq,
                                                    const float* __restrict__ Wk,
                                                    const float* __restrict__ Wv,
                                                    unsigned short* __restrict__ Wt) {
  __shared__ unsigned short tile[64][65];
  const float* s = (blockIdx.z == 0) ? Wq : (blockIdx.z == 1) ? Wk : Wv;
  unsigned short* d = Wt + (size_t)blockIdx.z * D_ * KC_;
  const int r0 = blockIdx.x * 64, c0 = blockIdx.y * 64;
  const int tc = threadIdx.x & 63, tg = threadIdx.x >> 6;
#pragma unroll
  for (int i = 0; i < 16; i++) {
    const int r = i * 4 + tg;
    tile[r][tc] = f2bf(s[(size_t)(r0 + r) * D_ + (c0 + tc)]);
  }
  __syncthreads();
#pragma unroll
  for (int i = 0; i < 16; i++) {
    const int rr = i * 4 + tg;
    d[(size_t)(c0 + rr) * KC_ + (r0 + tc)] = tile[tc][rr];
  }
}

// ---------------- V transpose ----------------
__global__ __launch_bounds__(256) void transpose_v(const unsigned short* __restrict__ src,
                                                   unsigned short* __restrict__ dst) {
  __shared__ unsigned short tile[64][65];
  const unsigned short* s = src + (size_t)blockIdx.z * T_ * KC_;
  unsigned short* d = dst + (size_t)blockIdx.z * D_ * T_;
  const int r0 = blockIdx.x * 64, c0 = blockIdx.y * 64;
  const int tc = threadIdx.x & 63, tg = threadIdx.x >> 6;
#pragma unroll
  for (int i = 0; i < 16; i++) {
    const int r = i * 4 + tg;
    tile[r][tc] = s[(size_t)(r0 + r) * KC_ + (c0 + tc)];
  }
  __syncthreads();
#pragma unroll
  for (int i = 0; i < 16; i++) {
    const int rr = i * 4 + tg;
    d[(size_t)(c0 + rr) * T_ + (r0 + tc)] = tile[tc][rr];
  }
}

// ---------------- combine: inv[k] = 1 / sum of 8 partial colsums ----------------
__global__ __launch_bounds__(256) void stats_combine(const float* __restrict__ pl,
                                                     long long sPz,
                                                     float* __restrict__ inv,
                                                     long long sIz) {
  const size_t z = blockIdx.z;
  const int col = blockIdx.x * 256 + threadIdx.x;
  float L = 0.f;
#pragma unroll
  for (int mb = 0; mb < 8; mb++)
    L += pl[z * (size_t)sPz + (size_t)mb * T_ + col];
  inv[z * (size_t)sIz + col] = 1.0f / L;
}

// ---------------- scale Vt rows: Vt[d][k] *= inv[k] ----------------
__global__ __launch_bounds__(256) void scale_vt(unsigned short* __restrict__ Vt,
                                                long long sVz,
                                                const float* __restrict__ inv,
                                                long long sIz) {
  const size_t z = blockIdx.z;
  unsigned short* Vb = Vt + z * (size_t)sVz;
  const float* iv = inv + z * (size_t)sIz;
  const int idx = (blockIdx.x * 256 + threadIdx.x) * 8;  // grid.x=512 -> 512*2048
  const int k = idx & (T_ - 1);
  short8 v = *(const short8*)(Vb + idx);
  float4v i0 = *(const float4v*)(iv + k);
  float4v i1 = *(const float4v*)(iv + k + 4);
  short8 o;
#pragma unroll
  for (int j = 0; j < 8; j++) {
    float s = (j < 4) ? i0[j & 3] : i1[j & 3];
    o[j] = (short)f2bf(bf2f((unsigned short)v[j]) * s);
  }
  *(short8*)(Vb + idx) = o;
}

// ================= 8-phase BM=256 GEMM: C = A * B'^T =================
// A [M][K] bf16 row-major (lda), B' [N][K] bf16 row-major (ldb), BK=64.
// Wave grid WM x WN (8 waves); per-wave output (256/WM) x (BN/WN).

#define RD_A(MH, BUF)                                                        \
  {                                                                          \
    const unsigned short* p_ =                                               \
        lds + (BUF) * 16384 + aoff + (MH) * (HFA * 1024);                    \
    _Pragma("unroll") for (int f_ = 0; f_ < HFA; ++f_) {                     \
      afr[MH][f_][0] = *(const short8*)(p_ + f_ * 1024 + q0);                \
      afr[MH][f_][1] = *(const short8*)(p_ + f_ * 1024 + q1);                \
    }                                                                        \
  }

#define RD_B(NH, BUF)                                                        \
  {                                                                          \
    const unsigned short* p_ =                                               \
        lds + 32768 + (BUF) * BLD + boff + (NH) * (HFB * 1024);              \
    _Pragma("unroll") for (int f_ = 0; f_ < HFB; ++f_) {                     \
      bfr[NH][f_][0] = *(const short8*)(p_ + f_ * 1024 + q0);                \
      bfr[NH][f_][1] = *(const short8*)(p_ + f_ * 1024 + q1);                \
    }                                                                        \
  }

#define MMA(MH, NH)                                                          \
  __builtin_amdgcn_s_setprio(1);                                             \
  _Pragma("unroll") for (int s_ = 0; s_ < 2; ++s_)                           \
  _Pragma("unroll") for (int f_ = 0; f_ < HFA; ++f_)                         \
  _Pragma("unroll") for (int g_ = 0; g_ < HFB; ++g_)                         \
      acc[(MH) * HFA + f_][(NH) * HFB + g_] =                                \
          mfma16(afr[MH][f_][s_], bfr[NH][g_][s_],                           \
                 acc[(MH) * HFA + f_][(NH) * HFB + g_]);                     \
  __builtin_amdgcn_s_setprio(0);

#define PH_MID                                                               \
  __builtin_amdgcn_s_barrier();                                              \
  asm volatile("s_waitcnt lgkmcnt(0)" ::: "memory");                         \
  __builtin_amdgcn_sched_barrier(0);

#define PH_END __builtin_amdgcn_s_barrier();

#define VMW                                                                  \
  do {                                                                       \
    if constexpr (GB == 4)                                                   \
      asm volatile("s_waitcnt vmcnt(4)" ::: "memory");                       \
    else if constexpr (GB == 3)                                              \
      asm volatile("s_waitcnt vmcnt(3)" ::: "memory");                       \
    else                                                                     \
      asm volatile("s_waitcnt vmcnt(2)" ::: "memory");                       \
  } while (0)

template <int MODE, int BN, int WM, int WN>
__global__ __launch_bounds__(512, 2)
void gemm8(const unsigned short* __restrict__ A, long long sAz, int lda,
           const unsigned short* __restrict__ Bm, long long sBz, int ldb,
           void* __restrict__ Out, long long sOz, int ldo,
           const float* __restrict__ bias,
           float* __restrict__ pl, long long sPz,
           int Kdim, float scale) {
  constexpr int RW  = 256 / WM;     // rows per wave
  constexpr int CW  = BN / WN;      // cols per wave
  constexpr int FA  = RW / 16;      // A frags per wave
  constexpr int FB  = CW / 16;      // B frags per wave
  constexpr int HFA = FA / 2;
  constexpr int HFB = FB / 2;
  constexpr int GB  = BN / 64;      // B staging gld16s per tile
  constexpr int GBP2 = (GB + 1) / 2;
  constexpr int BLD = BN * 64;      // elems per B buffer
  __shared__ unsigned short lds[32768 + 2 * BLD];   // A dbuf 64K + B dbuf

  const int tid = threadIdx.x;
  const int l = tid & 63;
  const int wv = tid >> 6;
  const int wm = wv / WN, wn = wv % WN;
  const int l15 = l & 15, hi = l >> 4, l7 = l & 7;
  const size_t z = blockIdx.z;
  const unsigned short* Ab = A + z * (size_t)sAz;
  const unsigned short* Bb = Bm + z * (size_t)sBz;
  const int m0 = blockIdx.x * 256, n0 = blockIdx.y * BN;
  const int NT = Kdim >> 6;
  const int NIT = NT >> 1;

  // ---- staging: LDS linear [row][8 chunks of 16B]; global pre-swizzled
  //      so LDS[row][p] holds global chunk p ^ (row&7).
  const int srow = tid >> 3;                                  // 0..63
  const int cswz = ((tid & 7) ^ ((tid >> 3) & 7)) << 3;       // elem offset
  const unsigned short* gA = Ab + (size_t)(m0 + srow) * lda + cswz;
  const unsigned short* gB = Bb + (size_t)(n0 + srow) * ldb + cswz;

  auto stgA = [&](int buf, int h, int kt) {
    if (kt >= NT) kt = NT - 1;                      // tail: harmless reload
    unsigned short* d = lds + buf * 16384 + h * 8192 + tid * 8;
    const unsigned short* g = gA + (size_t)(h * 128) * lda + kt * 64;
    gld16(g, d);
    gld16(g + (size_t)64 * lda, d + 4096);
  };
  auto stgB = [&](int buf, int g, int kt) {         // g-th 64-row group
    if (kt >= NT) kt = NT - 1;
    unsigned short* d = lds + 32768 + buf * BLD + g * 4096 + tid * 8;
    const unsigned short* gp = gB + (size_t)(g * 64) * ldb + kt * 64;
    gld16(gp, d);
  };

  // ---- fragment read addressing (inverse swizzle on ds_read_b128)
  const int aoff = (wm * RW + l15) * 64;
  const int boff = (wn * CW + l15) * 64;
  const int q0 = ((0 + hi) ^ l7) << 3;              // k-slice 0 chunk
  const int q1 = ((4 + hi) ^ l7) << 3;              // k-slice 1 chunk

  short8 afr[2][HFA][2];
  short8 bfr[2][HFB][2];
  float4v acc[FA][FB];
#pragma unroll
  for (int i = 0; i < FA; ++i)
#pragma unroll
    for (int j = 0; j < FB; ++j)
#pragma unroll
      for (int r = 0; r < 4; ++r) acc[i][j][r] = 0.f;

  // ---- prologue: tile0 fully + tile1 B; leave tile1.B in flight
#pragma unroll
  for (int g = 0; g < GB; ++g) stgB(0, g, 0);
  stgA(0, 0, 0); stgA(0, 1, 0);
#pragma unroll
  for (int g = 0; g < GB; ++g) stgB(1, g, 1);
  VMW;
  __builtin_amdgcn_s_barrier();
  __builtin_amdgcn_sched_barrier(0);

  // ---- main loop: 8 phases = 2 K-tiles. vmcnt(GB) at p3/p7 only.
  for (int it = 0; it < NIT; ++it) {
    const int kt = 2 * it;
    // p0: q(0,0) buf0      | stage A0(t+1)->buf1
    RD_A(0, 0); RD_B(0, 0);
    stgA(1, 0, kt + 1);
    PH_MID; MMA(0, 0); PH_END;
    // p1: q(0,1) buf0      | stage A1(t+1)->buf1
    RD_B(1, 0);
    stgA(1, 1, kt + 1);
    PH_MID; MMA(0, 1); PH_END;
    // p2: q(1,1) buf0      | stage B[0..GBP2)(t+2)->buf0
    RD_A(1, 0);
#pragma unroll
    for (int g = 0; g < GBP2; ++g) stgB(0, g, kt + 2);
    PH_MID; MMA(1, 1); PH_END;
    // p3: q(1,0) buf0      | stage B[GBP2..GB)(t+2)->buf0 ; vmcnt -> t+1 landed
#pragma unroll
    for (int g = GBP2; g < GB; ++g) stgB(0, g, kt + 2);
    PH_MID; MMA(1, 0); VMW; PH_END;
    // p4: q(0,0) buf1      | stage A0(t+2)->buf0
    RD_A(0, 1); RD_B(0, 1);
    stgA(0, 0, kt + 2);
    PH_MID; MMA(0, 0); PH_END;
    // p5: q(0,1) buf1      | stage A1(t+2)->buf0
    RD_B(1, 1);
    stgA(0, 1, kt + 2);
    PH_MID; MMA(0, 1); PH_END;
    // p6: q(1,1) buf1      | stage B[0..GBP2)(t+3)->buf1
    RD_A(1, 1);
#pragma unroll
    for (int g = 0; g < GBP2; ++g) stgB(1, g, kt + 3);
    PH_MID; MMA(1, 1); PH_END;
    // p7: q(1,0) buf1      | stage B[GBP2..GB)(t+3)->buf1 ; vmcnt -> t+2 landed
#pragma unroll
    for (int g = GBP2; g < GB; ++g) stgB(1, g, kt + 3);
    PH_MID; MMA(1, 0); VMW; PH_END;
  }

  // ---- epilogue: C/D col = lane&15, row = (lane>>4)*4 + reg
  const int r0 = m0 + wm * RW + hi * 4;
  const int c0 = n0 + wn * CW + l15;

  if constexpr (MODE == 2) {
    float* O = (float*)Out + z * (size_t)sOz;
#pragma unroll
    for (int fm = 0; fm < FA; ++fm)
#pragma unroll
      for (int fn = 0; fn < FB; ++fn)
#pragma unroll
        for (int r = 0; r < 4; ++r)
          O[(size_t)(r0 + fm * 16 + r) * ldo + (c0 + fn * 16)] =
              acc[fm][fn][r] * scale;
  } else if constexpr (MODE == 0) {
    unsigned short* O = (unsigned short*)Out + z * (size_t)sOz;
#pragma unroll
    for (int fn = 0; fn < FB; ++fn) {
      const float badd = bias[c0 + fn * 16];
#pragma unroll
      for (int fm = 0; fm < FA; ++fm)
#pragma unroll
        for (int r = 0; r < 4; ++r)
          O[(size_t)(r0 + fm * 16 + r) * ldo + (c0 + fn * 16)] =
              f2bf(acc[fm][fn][r] * scale + badd);
    }
  } else {  // MODE 1: P_raw = exp(S*scale - 16) + per-block column sums
    unsigned short* O = (unsigned short*)Out + z * (size_t)sOz;
    float cs[FB];
#pragma unroll
    for (int fn = 0; fn < FB; ++fn) cs[fn] = 0.f;
#pragma unroll
    for (int fm = 0; fm < FA; ++fm)
#pragma unroll
      for (int fn = 0; fn < FB; ++fn)
#pragma unroll
        for (int r = 0; r < 4; ++r) {
          float e = __expf(acc[fm][fn][r] * scale - 16.f);   // |S*scale| <~ 25
          cs[fn] += e;
          O[(size_t)(r0 + fm * 16 + r) * ldo + (c0 + fn * 16)] = f2bf(e);
        }
    // reduce over the 4 row-groups (lane>>4) inside the wave
#pragma unroll
    for (int fn = 0; fn < FB; ++fn) {
      cs[fn] += __shfl_xor(cs[fn], 16, 64);
      cs[fn] += __shfl_xor(cs[fn], 32, 64);
    }
    __syncthreads();
    float* red = (float*)(lds + 32768);     // scratch in buf0-B region: tail
    if (hi == 0) {                          // stages only target buf1-B here
#pragma unroll
      for (int fn = 0; fn < FB; ++fn)
        red[wm * BN + wn * CW + fn * 16 + l15] = cs[fn];
    }
    __syncthreads();
    if (tid < BN)
      pl[z * (size_t)sPz + (size_t)blockIdx.x * T_ + (n0 + tid)] =
          red[tid] + red[BN + tid];
  }
}

// ---------------- host ----------------
extern "C" void kernel_launch(void* const* d_in, const int* in_sizes, int n_in,
                              void* d_out, int out_size, void* d_ws, size_t ws_size,
                              hipStream_t stream) {
  const float* x  = (const float*)d_in[0];
  const float* Wq = (const float*)d_in[1];
  const float* bq = (const float*)d_in[2];
  const float* Wk = (const float*)d_in[3];
  const float* bk = (const float*)d_in[4];
  const float* Wv = (const float*)d_in[5];
  const float* bv = (const float*)d_in[6];

  char* ws = (char*)d_ws;
  auto alloc = [&](size_t bytes) {
    char* p = ws; ws += (bytes + 255) & ~(size_t)255; return p;
  };
  unsigned short* xpad = (unsigned short*)alloc((size_t)B_ * TPAD_ * D_ * 2);
  unsigned short* Wt   = (unsigned short*)alloc((size_t)KC_ * KC_ * 2);     // [1536 u][1536 k]
  float*          bcat = (float*)alloc((size_t)KC_ * 4);
  unsigned short* QKV  = (unsigned short*)alloc((size_t)B_ * T_ * KC_ * 2); // [B][T][1536]
  unsigned short* Vt   = (unsigned short*)alloc((size_t)B_ * D_ * T_ * 2);
  float* invb = (float*)alloc((size_t)B_ * T_ * 4);
  float* pl   = (float*)alloc((size_t)B_ * 8 * T_ * 4);
  size_t used = (size_t)(ws - (char*)d_ws);
  const size_t sAll = (size_t)B_ * T_ * T_ * 2;   // bf16 P, all batches
  const size_t sOne = (size_t)T_ * T_ * 2;
  const int NB = (used + sAll <= ws_size) ? B_ : 1;  // ws-adaptive batching
  unsigned short* Sb = (unsigned short*)alloc(NB == B_ ? sAll : sOne);

  prep_x<<<dim3(1025, B_), 256, 0, stream>>>(x, xpad);
  concat_bias<<<dim3(6), 256, 0, stream>>>(bq, bk, bv, bcat);
  transpose_w3<<<dim3(24, 8, 3), 256, 0, stream>>>(Wq, Wk, Wv, Wt);

  // one QKV GEMM: M=2048/batch, N=1536, K=1536; BN=192 -> grid 8x8x8 = 512
  // blocks = exactly 2.0 dispatch rounds on 256 CUs (384 was 1.5 -> 25% tail).
  gemm8<0, 192, 4, 2><<<dim3(8, 8, B_), 512, 0, stream>>>(
      xpad, (long long)TPAD_ * D_, D_,
      Wt, 0, KC_,
      QKV, (long long)T_ * KC_, KC_,
      bcat, nullptr, 0, KC_, 1.0f);

  // V slice [T][512] (row stride 1536) -> Vt [512][2048]
  transpose_v<<<dim3(32, 8, B_), 256, 0, stream>>>(QKV + 2 * D_, Vt);

  const float scale = 0.044194173824159216f;  // 1/sqrt(512)
  for (int b0 = 0; b0 < B_; b0 += NB) {
    const unsigned short* Qp = QKV + (size_t)b0 * T_ * KC_;          // +0
    const unsigned short* Kp = QKV + (size_t)b0 * T_ * KC_ + D_;     // +512
    // P_raw = exp(S-16) + partial column sums (8 m-blocks)
    gemm8<1, 256, 2, 4><<<dim3(8, 8, NB), 512, 0, stream>>>(
        Qp, (long long)T_ * KC_, KC_,
        Kp, (long long)T_ * KC_, KC_,
        Sb, (long long)T_ * T_, T_,
        nullptr, pl + (size_t)b0 * 8 * T_, (long long)8 * T_,
        D_, scale);
    stats_combine<<<dim3(8, 1, NB), 256, 0, stream>>>(
        pl + (size_t)b0 * 8 * T_, (long long)8 * T_,
        invb + (size_t)b0 * T_, T_);
    scale_vt<<<dim3(512, 1, NB), 256, 0, stream>>>(
        Vt + (size_t)b0 * D_ * T_, (long long)D_ * T_,
        invb + (size_t)b0 * T_, T_);
    // ctx: out = P_raw @ Vt'^T, 256x128 tiles -> 256 blocks (1/CU)
    gemm8<2, 128, 2, 4><<<dim3(8, 4, NB), 512, 0, stream>>>(
        Sb, (long long)T_ * T_, T_,
        Vt + (size_t)b0 * D_ * T_, (long long)D_ * T_, T_,
        (float*)d_out + (size_t)b0 * T_ * D_, (long long)T_ * D_, D_,
        nullptr, nullptr, 0, T_, 1.0f);
  }
}

// Round 3
// 267.930 us; speedup vs baseline: 1.2070x; 1.0543x over previous
//
#include <hip/hip_runtime.h>

// Conv_Attention: q,k,v = causal_conv1d(x, W*) ; S = qk^T/sqrt(U);
// softmax over QUERY axis (per-column of S); out = P @ v.
// B=8, T=2048, Cin=U=512, K=3.
//
// Round 10: round-9 steady state = ~1010 cyc/phase of which only ~466 is MFMA
// -> ~500 cyc/phase barrier stall, unhidable at 1 block/CU (LDS 112KB).
// Restructure all GEMMs to 4-wave blocks (256 thr), BM=128, LDS <= 80KB ->
// 2 blocks/CU: one block's barrier/lgkm drain overlaps the other's MFMA.
//  - QKV:    BN=192, grid 16x8x8  = 1024 blocks = 2.0 rounds of 512 slots
//  - scores: BN=128, grid 16x16x8 = 2048 = 4.0 rounds (16 colsum partials)
//  - ctx:    BN=128, grid 16x4x8  = 512  = 2.0 rounds (wave tile now 64x64,
//            was a degenerate 128x32)
//
// vmcnt ledger (GA=4 A-loads/tile, GB=BN/32 B-loads/tile):
//   prologue B(t0)[GB] A(t0)[GA] B(t1)[GB]; vmcnt(GB) retires t0.
//   loop p0/p1 +A(t+1)[GA], p2/p3 +B(t+2)[GB]; at p3 outstanding =
//   GB+GA+GB, vmcnt(GB) retires B(t+1)+A(t+1); symmetric at p7.
//   Never vmcnt(0) in the loop.

#define B_   8
#define T_   2048
#define D_   512
#define KC_  1536
#define TPAD_ 2050

using short8   = __attribute__((ext_vector_type(8))) short;
using float4v  = __attribute__((ext_vector_type(4))) float;

__device__ __forceinline__ float bf2f(unsigned short b) {
  unsigned u = ((unsigned)b) << 16;
  float f; __builtin_memcpy(&f, &u, 4); return f;
}
__device__ __forceinline__ unsigned short f2bf(float f) {
  unsigned u; __builtin_memcpy(&u, &f, 4);
  u += 0x7fffu + ((u >> 16) & 1u);          // RNE (finite inputs only)
  return (unsigned short)(u >> 16);
}

__device__ __forceinline__ void gld16(const void* g, void* l) {
  __builtin_amdgcn_global_load_lds((__attribute__((address_space(1))) void*)g,
                                   (__attribute__((address_space(3))) void*)l,
                                   16, 0, 0);
}

__device__ __forceinline__ float4v mfma16(short8 a, short8 b, float4v c) {
  return __builtin_amdgcn_mfma_f32_16x16x32_bf16(a, b, c, 0, 0, 0);
}

// ---------------- prep: pad + cast x ----------------
__global__ __launch_bounds__(256) void prep_x(const float* __restrict__ x,
                                              unsigned short* __restrict__ xpad) {
  const int b = blockIdx.y;
  const int i = (blockIdx.x * 256 + threadIdx.x) * 4;   // grid.x=1025 -> exactly 2050*512
  const int t = i >> 9;
  unsigned short* dst = xpad + (size_t)b * (TPAD_ * D_) + i;
  if (t < 2) {
    dst[0] = 0; dst[1] = 0; dst[2] = 0; dst[3] = 0;
  } else {
    const float* sp = x + ((size_t)b * T_ + (t - 2)) * D_ + (i & 511);
    float4v v = *(const float4v*)sp;
    dst[0] = f2bf(v[0]); dst[1] = f2bf(v[1]); dst[2] = f2bf(v[2]); dst[3] = f2bf(v[3]);
  }
}

// ---------------- bias concat ----------------
__global__ __launch_bounds__(256) void concat_bias(const float* __restrict__ bq,
                                                   const float* __restrict__ bk,
                                                   const float* __restrict__ bv,
                                                   float* __restrict__ out) {
  const int i = blockIdx.x * 256 + threadIdx.x;   // grid 6 -> 1536
  float v = (i < 512) ? bq[i] : ((i < 1024) ? bk[i - 512] : bv[i - 1024]);
  out[i] = v;
}

// ---------------- W transpose, all three in one launch ----------------
__global__ __launch_bounds__(256) void transpose_w3(const float* __restrict__ Wq,
                                                    const float* __restrict__ Wk,
                                                    const float* __restrict__ Wv,
                                                    unsigned short* __restrict__ Wt) {
  __shared__ unsigned short tile[64][65];
  const float* s = (blockIdx.z == 0) ? Wq : (blockIdx.z == 1) ? Wk : Wv;
  unsigned short* d = Wt + (size_t)blockIdx.z * D_ * KC_;
  const int r0 = blockIdx.x * 64, c0 = blockIdx.y * 64;
  const int tc = threadIdx.x & 63, tg = threadIdx.x >> 6;
#pragma unroll
  for (int i = 0; i < 16; i++) {
    const int r = i * 4 + tg;
    tile[r][tc] = f2bf(s[(size_t)(r0 + r) * D_ + (c0 + tc)]);
  }
  __syncthreads();
#pragma unroll
  for (int i = 0; i < 16; i++) {
    const int rr = i * 4 + tg;
    d[(size_t)(c0 + rr) * KC_ + (r0 + tc)] = tile[tc][rr];
  }
}

// ---------------- V transpose ----------------
__global__ __launch_bounds__(256) void transpose_v(const unsigned short* __restrict__ src,
                                                   unsigned short* __restrict__ dst) {
  __shared__ unsigned short tile[64][65];
  const unsigned short* s = src + (size_t)blockIdx.z * T_ * KC_;
  unsigned short* d = dst + (size_t)blockIdx.z * D_ * T_;
  const int r0 = blockIdx.x * 64, c0 = blockIdx.y * 64;
  const int tc = threadIdx.x & 63, tg = threadIdx.x >> 6;
#pragma unroll
  for (int i = 0; i < 16; i++) {
    const int r = i * 4 + tg;
    tile[r][tc] = s[(size_t)(r0 + r) * KC_ + (c0 + tc)];
  }
  __syncthreads();
#pragma unroll
  for (int i = 0; i < 16; i++) {
    const int rr = i * 4 + tg;
    d[(size_t)(c0 + rr) * T_ + (r0 + tc)] = tile[tc][rr];
  }
}

// ---------------- combine: inv[k] = 1 / sum of 16 partial colsums ----------------
__global__ __launch_bounds__(256) void stats_combine(const float* __restrict__ pl,
                                                     long long sPz,
                                                     float* __restrict__ inv,
                                                     long long sIz) {
  const size_t z = blockIdx.z;
  const int col = blockIdx.x * 256 + threadIdx.x;
  float L = 0.f;
#pragma unroll
  for (int mb = 0; mb < 16; mb++)
    L += pl[z * (size_t)sPz + (size_t)mb * T_ + col];
  inv[z * (size_t)sIz + col] = 1.0f / L;
}

// ---------------- scale Vt rows: Vt[d][k] *= inv[k] ----------------
__global__ __launch_bounds__(256) void scale_vt(unsigned short* __restrict__ Vt,
                                                long long sVz,
                                                const float* __restrict__ inv,
                                                long long sIz) {
  const size_t z = blockIdx.z;
  unsigned short* Vb = Vt + z * (size_t)sVz;
  const float* iv = inv + z * (size_t)sIz;
  const int idx = (blockIdx.x * 256 + threadIdx.x) * 8;  // grid.x=512 -> 512*2048
  const int k = idx & (T_ - 1);
  short8 v = *(const short8*)(Vb + idx);
  float4v i0 = *(const float4v*)(iv + k);
  float4v i1 = *(const float4v*)(iv + k + 4);
  short8 o;
#pragma unroll
  for (int j = 0; j < 8; j++) {
    float s = (j < 4) ? i0[j & 3] : i1[j & 3];
    o[j] = (short)f2bf(bf2f((unsigned short)v[j]) * s);
  }
  *(short8*)(Vb + idx) = o;
}

// ================= 8-phase BM=128 / 4-wave GEMM: C = A * B'^T =================
// A [M][K] bf16 row-major (lda), B' [N][K] bf16 row-major (ldb), BK=64.
// 256 threads; wave grid 2x2; per-wave output 64 x (BN/2). LDS <= 80KB ->
// 2 blocks/CU so one block's barrier stall hides under the other's MFMA.

#define RD_A(MH, BUF)                                                        \
  {                                                                          \
    const unsigned short* p_ =                                               \
        lds + (BUF) * 8192 + aoff + (MH) * (HFA * 1024);                     \
    _Pragma("unroll") for (int f_ = 0; f_ < HFA; ++f_) {                     \
      afr[MH][f_][0] = *(const short8*)(p_ + f_ * 1024 + q0);                \
      afr[MH][f_][1] = *(const short8*)(p_ + f_ * 1024 + q1);                \
    }                                                                        \
  }

#define RD_B(NH, BUF)                                                        \
  {                                                                          \
    const unsigned short* p_ =                                               \
        lds + 16384 + (BUF) * BLD + boff + (NH) * (HFB * 1024);              \
    _Pragma("unroll") for (int f_ = 0; f_ < HFB; ++f_) {                     \
      bfr[NH][f_][0] = *(const short8*)(p_ + f_ * 1024 + q0);                \
      bfr[NH][f_][1] = *(const short8*)(p_ + f_ * 1024 + q1);                \
    }                                                                        \
  }

#define MMA(MH, NH)                                                          \
  __builtin_amdgcn_s_setprio(1);                                             \
  _Pragma("unroll") for (int s_ = 0; s_ < 2; ++s_)                           \
  _Pragma("unroll") for (int f_ = 0; f_ < HFA; ++f_)                         \
  _Pragma("unroll") for (int g_ = 0; g_ < HFB; ++g_)                         \
      acc[(MH) * HFA + f_][(NH) * HFB + g_] =                                \
          mfma16(afr[MH][f_][s_], bfr[NH][g_][s_],                           \
                 acc[(MH) * HFA + f_][(NH) * HFB + g_]);                     \
  __builtin_amdgcn_s_setprio(0);

#define PH_MID                                                               \
  __builtin_amdgcn_s_barrier();                                              \
  asm volatile("s_waitcnt lgkmcnt(0)" ::: "memory");                         \
  __builtin_amdgcn_sched_barrier(0);

#define PH_END __builtin_amdgcn_s_barrier();

#define VMW                                                                  \
  do {                                                                       \
    if constexpr (GB == 6)                                                   \
      asm volatile("s_waitcnt vmcnt(6)" ::: "memory");                       \
    else                                                                     \
      asm volatile("s_waitcnt vmcnt(4)" ::: "memory");                       \
  } while (0)

template <int MODE, int BN>
__global__ __launch_bounds__(256, 2)
void gemm8(const unsigned short* __restrict__ A, long long sAz, int lda,
           const unsigned short* __restrict__ Bm, long long sBz, int ldb,
           void* __restrict__ Out, long long sOz, int ldo,
           const float* __restrict__ bias,
           float* __restrict__ pl, long long sPz,
           int Kdim, float scale) {
  constexpr int RW  = 64;           // rows per wave (BM=128, wave grid 2x2)
  constexpr int CW  = BN / 2;       // cols per wave
  constexpr int FA  = 4;            // A frags per wave
  constexpr int FB  = CW / 16;      // B frags per wave (6 or 4)
  constexpr int HFA = 2;
  constexpr int HFB = FB / 2;
  constexpr int GB  = BN / 32;      // B staging gld16s per tile (6 or 4)
  constexpr int GBP2 = GB / 2;
  constexpr int BLD = BN * 64;      // elems per B buffer
  // A dbuf = 2 x 8192 elems (32KB); B dbuf = 2 x BLD
  __shared__ unsigned short lds[16384 + 2 * BLD];

  const int tid = threadIdx.x;
  const int l = tid & 63;
  const int wv = tid >> 6;
  const int wm = wv >> 1, wn = wv & 1;
  const int l15 = l & 15, hi = l >> 4, l7 = l & 7;
  const size_t z = blockIdx.z;
  const unsigned short* Ab = A + z * (size_t)sAz;
  const unsigned short* Bb = Bm + z * (size_t)sBz;
  const int m0 = blockIdx.x * 128, n0 = blockIdx.y * BN;
  const int NT = Kdim >> 6;
  const int NIT = NT >> 1;

  // ---- staging: LDS linear [row][8 chunks of 16B]; global pre-swizzled
  //      so LDS[row][p] holds global chunk p ^ (row&7). 256 thr -> one gld16
  //      covers 32 rows (4096B).
  const int srow = tid >> 3;                                  // 0..31
  const int cswz = ((tid & 7) ^ ((tid >> 3) & 7)) << 3;       // elem offset
  const unsigned short* gA = Ab + (size_t)(m0 + srow) * lda + cswz;
  const unsigned short* gB = Bb + (size_t)(n0 + srow) * ldb + cswz;

  auto stgA = [&](int buf, int h, int kt) {        // h-th 64-row half
    if (kt >= NT) kt = NT - 1;                      // tail: harmless reload
    unsigned short* d = lds + buf * 8192 + h * 4096 + tid * 8;
    const unsigned short* g = gA + (size_t)(h * 64) * lda + kt * 64;
    gld16(g, d);
    gld16(g + (size_t)32 * lda, d + 2048);
  };
  auto stgB = [&](int buf, int g, int kt) {         // g-th 32-row group
    if (kt >= NT) kt = NT - 1;
    unsigned short* d = lds + 16384 + buf * BLD + g * 2048 + tid * 8;
    const unsigned short* gp = gB + (size_t)(g * 32) * ldb + kt * 64;
    gld16(gp, d);
  };

  // ---- fragment read addressing (inverse swizzle on ds_read_b128)
  const int aoff = (wm * RW + l15) * 64;
  const int boff = (wn * CW + l15) * 64;
  const int q0 = ((0 + hi) ^ l7) << 3;              // k-slice 0 chunk
  const int q1 = ((4 + hi) ^ l7) << 3;              // k-slice 1 chunk

  short8 afr[2][HFA][2];
  short8 bfr[2][HFB][2];
  float4v acc[FA][FB];
#pragma unroll
  for (int i = 0; i < FA; ++i)
#pragma unroll
    for (int j = 0; j < FB; ++j)
#pragma unroll
      for (int r = 0; r < 4; ++r) acc[i][j][r] = 0.f;

  // ---- prologue: tile0 fully + tile1 B; leave tile1.B in flight
#pragma unroll
  for (int g = 0; g < GB; ++g) stgB(0, g, 0);
  stgA(0, 0, 0); stgA(0, 1, 0);
#pragma unroll
  for (int g = 0; g < GB; ++g) stgB(1, g, 1);
  VMW;
  __builtin_amdgcn_s_barrier();
  __builtin_amdgcn_sched_barrier(0);

  // ---- main loop: 8 phases = 2 K-tiles. vmcnt(GB) at p3/p7 only.
  for (int it = 0; it < NIT; ++it) {
    const int kt = 2 * it;
    // p0: q(0,0) buf0      | stage A0(t+1)->buf1
    RD_A(0, 0); RD_B(0, 0);
    stgA(1, 0, kt + 1);
    PH_MID; MMA(0, 0); PH_END;
    // p1: q(0,1) buf0      | stage A1(t+1)->buf1
    RD_B(1, 0);
    stgA(1, 1, kt + 1);
    PH_MID; MMA(0, 1); PH_END;
    // p2: q(1,1) buf0      | stage B[0..GBP2)(t+2)->buf0
    RD_A(1, 0);
#pragma unroll
    for (int g = 0; g < GBP2; ++g) stgB(0, g, kt + 2);
    PH_MID; MMA(1, 1); PH_END;
    // p3: q(1,0) buf0      | stage B[GBP2..GB)(t+2)->buf0 ; vmcnt -> t+1 landed
#pragma unroll
    for (int g = GBP2; g < GB; ++g) stgB(0, g, kt + 2);
    PH_MID; MMA(1, 0); VMW; PH_END;
    // p4: q(0,0) buf1      | stage A0(t+2)->buf0
    RD_A(0, 1); RD_B(0, 1);
    stgA(0, 0, kt + 2);
    PH_MID; MMA(0, 0); PH_END;
    // p5: q(0,1) buf1      | stage A1(t+2)->buf0
    RD_B(1, 1);
    stgA(0, 1, kt + 2);
    PH_MID; MMA(0, 1); PH_END;
    // p6: q(1,1) buf1      | stage B[0..GBP2)(t+3)->buf1
    RD_A(1, 1);
#pragma unroll
    for (int g = 0; g < GBP2; ++g) stgB(1, g, kt + 3);
    PH_MID; MMA(1, 1); PH_END;
    // p7: q(1,0) buf1      | stage B[GBP2..GB)(t+3)->buf1 ; vmcnt -> t+2 landed
#pragma unroll
    for (int g = GBP2; g < GB; ++g) stgB(1, g, kt + 3);
    PH_MID; MMA(1, 0); VMW; PH_END;
  }

  // ---- epilogue: C/D col = lane&15, row = (lane>>4)*4 + reg
  const int r0 = m0 + wm * RW + hi * 4;
  const int c0 = n0 + wn * CW + l15;

  if constexpr (MODE == 2) {
    float* O = (float*)Out + z * (size_t)sOz;
#pragma unroll
    for (int fm = 0; fm < FA; ++fm)
#pragma unroll
      for (int fn = 0; fn < FB; ++fn)
#pragma unroll
        for (int r = 0; r < 4; ++r)
          O[(size_t)(r0 + fm * 16 + r) * ldo + (c0 + fn * 16)] =
              acc[fm][fn][r] * scale;
  } else if constexpr (MODE == 0) {
    unsigned short* O = (unsigned short*)Out + z * (size_t)sOz;
#pragma unroll
    for (int fn = 0; fn < FB; ++fn) {
      const float badd = bias[c0 + fn * 16];
#pragma unroll
      for (int fm = 0; fm < FA; ++fm)
#pragma unroll
        for (int r = 0; r < 4; ++r)
          O[(size_t)(r0 + fm * 16 + r) * ldo + (c0 + fn * 16)] =
              f2bf(acc[fm][fn][r] * scale + badd);
    }
  } else {  // MODE 1: P_raw = exp(S*scale - 16) + per-block column sums
    unsigned short* O = (unsigned short*)Out + z * (size_t)sOz;
    float cs[FB];
#pragma unroll
    for (int fn = 0; fn < FB; ++fn) cs[fn] = 0.f;
#pragma unroll
    for (int fm = 0; fm < FA; ++fm)
#pragma unroll
      for (int fn = 0; fn < FB; ++fn)
#pragma unroll
        for (int r = 0; r < 4; ++r) {
          float e = __expf(acc[fm][fn][r] * scale - 16.f);   // |S*scale| <~ 25
          cs[fn] += e;
          O[(size_t)(r0 + fm * 16 + r) * ldo + (c0 + fn * 16)] = f2bf(e);
        }
    // reduce over the 4 row-groups (lane>>4) inside the wave
#pragma unroll
    for (int fn = 0; fn < FB; ++fn) {
      cs[fn] += __shfl_xor(cs[fn], 16, 64);
      cs[fn] += __shfl_xor(cs[fn], 32, 64);
    }
    __syncthreads();
    float* red = (float*)(lds + 16384);     // scratch = B-buf0 (landed by the
    if (hi == 0) {                          // final p7 vmcnt; in-flight tail
#pragma unroll                              // stages only target buf1)
      for (int fn = 0; fn < FB; ++fn)
        red[wm * BN + wn * CW + fn * 16 + l15] = cs[fn];
    }
    __syncthreads();
    if (tid < BN)
      pl[z * (size_t)sPz + (size_t)blockIdx.x * T_ + (n0 + tid)] =
          red[tid] + red[BN + tid];
  }
}

// ---------------- host ----------------
extern "C" void kernel_launch(void* const* d_in, const int* in_sizes, int n_in,
                              void* d_out, int out_size, void* d_ws, size_t ws_size,
                              hipStream_t stream) {
  const float* x  = (const float*)d_in[0];
  const float* Wq = (const float*)d_in[1];
  const float* bq = (const float*)d_in[2];
  const float* Wk = (const float*)d_in[3];
  const float* bk = (const float*)d_in[4];
  const float* Wv = (const float*)d_in[5];
  const float* bv = (const float*)d_in[6];

  char* ws = (char*)d_ws;
  auto alloc = [&](size_t bytes) {
    char* p = ws; ws += (bytes + 255) & ~(size_t)255; return p;
  };
  unsigned short* xpad = (unsigned short*)alloc((size_t)B_ * TPAD_ * D_ * 2);
  unsigned short* Wt   = (unsigned short*)alloc((size_t)KC_ * KC_ * 2);     // [1536 u][1536 k]
  float*          bcat = (float*)alloc((size_t)KC_ * 4);
  unsigned short* QKV  = (unsigned short*)alloc((size_t)B_ * T_ * KC_ * 2); // [B][T][1536]
  unsigned short* Vt   = (unsigned short*)alloc((size_t)B_ * D_ * T_ * 2);
  float* invb = (float*)alloc((size_t)B_ * T_ * 4);
  float* pl   = (float*)alloc((size_t)B_ * 16 * T_ * 4);
  size_t used = (size_t)(ws - (char*)d_ws);
  const size_t sAll = (size_t)B_ * T_ * T_ * 2;   // bf16 P, all batches
  const size_t sOne = (size_t)T_ * T_ * 2;
  const int NB = (used + sAll <= ws_size) ? B_ : 1;  // ws-adaptive batching
  unsigned short* Sb = (unsigned short*)alloc(NB == B_ ? sAll : sOne);

  prep_x<<<dim3(1025, B_), 256, 0, stream>>>(x, xpad);
  concat_bias<<<dim3(6), 256, 0, stream>>>(bq, bk, bv, bcat);
  transpose_w3<<<dim3(24, 8, 3), 256, 0, stream>>>(Wq, Wk, Wv, Wt);

  // QKV GEMM: M=2048/batch, N=1536, K=1536; BM=128/BN=192 -> 1024 blocks
  // = exactly 2.0 rounds of 512 block-slots (2 blocks/CU, LDS 80KB).
  gemm8<0, 192><<<dim3(16, 8, B_), 256, 0, stream>>>(
      xpad, (long long)TPAD_ * D_, D_,
      Wt, 0, KC_,
      QKV, (long long)T_ * KC_, KC_,
      bcat, nullptr, 0, KC_, 1.0f);

  // V slice [T][512] (row stride 1536) -> Vt [512][2048]
  transpose_v<<<dim3(32, 8, B_), 256, 0, stream>>>(QKV + 2 * D_, Vt);

  const float scale = 0.044194173824159216f;  // 1/sqrt(512)
  for (int b0 = 0; b0 < B_; b0 += NB) {
    const unsigned short* Qp = QKV + (size_t)b0 * T_ * KC_;          // +0
    const unsigned short* Kp = QKV + (size_t)b0 * T_ * KC_ + D_;     // +512
    // P_raw = exp(S-16) + partial column sums (16 m-blocks)
    gemm8<1, 128><<<dim3(16, 16, NB), 256, 0, stream>>>(
        Qp, (long long)T_ * KC_, KC_,
        Kp, (long long)T_ * KC_, KC_,
        Sb, (long long)T_ * T_, T_,
        nullptr, pl + (size_t)b0 * 16 * T_, (long long)16 * T_,
        D_, scale);
    stats_combine<<<dim3(8, 1, NB), 256, 0, stream>>>(
        pl + (size_t)b0 * 16 * T_, (long long)16 * T_,
        invb + (size_t)b0 * T_, T_);
    scale_vt<<<dim3(512, 1, NB), 256, 0, stream>>>(
        Vt + (size_t)b0 * D_ * T_, (long long)D_ * T_,
        invb + (size_t)b0 * T_, T_);
    // ctx: out = P_raw @ Vt'^T, 128x128 tiles -> 512 blocks = 2.0 rounds
    gemm8<2, 128><<<dim3(16, 4, NB), 256, 0, stream>>>(
        Sb, (long long)T_ * T_, T_,
        Vt + (size_t)b0 * D_ * T_, (long long)D_ * T_, T_,
        (float*)d_out + (size_t)b0 * T_ * D_, (long long)T_ * D_, D_,
        nullptr, nullptr, 0, T_, 1.0f);
  }
}